// Round 1
// baseline (764.062 us; speedup 1.0000x reference)
//
#include <hip/hip_runtime.h>

#define TT 2000
#define BB 64
#define HH 256
#define BH (BB*HH)

__device__ __forceinline__ float clip01(float x) { return fminf(fmaxf(x, 0.0f), 1.0f); }

// ---------------- transpose both weight matrices (256KB each) ----------------
__global__ void transpose2(const float* __restrict__ w_in, const float* __restrict__ w_rec,
                           float* __restrict__ w_inT, float* __restrict__ w_recT) {
    int idx = blockIdx.x * 256 + threadIdx.x;   // 65536 per matrix
    int k = idx >> 8, h = idx & 255;
    w_inT[idx]  = w_in[h * HH + k];             // w_inT[k][h] = w_in[h][k]
    w_recT[idx] = w_rec[h * HH + k];
}

// ---------------- f32 GEMM: xw[n,h] = sum_k X[n,k] * w_inT[k,h] ----------------
// n = b*T + t (input row order). Output written to out region at [t, b, h].
#define BM 64
#define BN 128
#define BK 64
__global__ __launch_bounds__(256) void gemm_xw(const float* __restrict__ X,
                                               const float* __restrict__ WT,
                                               float* __restrict__ OutXW) {
    __shared__ __align__(16) float XsT[BK][BM + 4];   // transposed: [k][row]
    __shared__ __align__(16) float Ws[BK][BN + 4];    // [k][col]
    int tid = threadIdx.x;
    int n0 = blockIdx.x * BM;
    int h0 = blockIdx.y * BN;
    int ty = tid >> 4, tx = tid & 15;   // ty: 4-row group, tx: 8-col group
    float acc[4][8] = {};

    for (int kc = 0; kc < HH; kc += BK) {
        // load X tile 64x64 (transposed into LDS)
        {
            int r = tid & 63, seg = (tid >> 6) * 16;
            const float* src = X + (size_t)(n0 + r) * HH + kc + seg;
#pragma unroll
            for (int q = 0; q < 4; q++) {
                float4 xv = *(const float4*)(src + q * 4);
                XsT[seg + q * 4 + 0][r] = xv.x;
                XsT[seg + q * 4 + 1][r] = xv.y;
                XsT[seg + q * 4 + 2][r] = xv.z;
                XsT[seg + q * 4 + 3][r] = xv.w;
            }
        }
        // load W tile 64x128 (contiguous from pre-transposed WT)
        {
            int kk = tid & 63, cs = (tid >> 6) * 32;
            const float* src = WT + (size_t)(kc + kk) * HH + h0 + cs;
#pragma unroll
            for (int q = 0; q < 8; q++) {
                float4 wv = *(const float4*)(src + q * 4);
                *(float4*)&Ws[kk][cs + q * 4] = wv;
            }
        }
        __syncthreads();
#pragma unroll 4
        for (int kk = 0; kk < BK; kk++) {
            float4 av = *(const float4*)&XsT[kk][ty * 4];
            float4 b0 = *(const float4*)&Ws[kk][tx * 8];
            float4 b1 = *(const float4*)&Ws[kk][tx * 8 + 4];
            float a[4] = {av.x, av.y, av.z, av.w};
            float bb[8] = {b0.x, b0.y, b0.z, b0.w, b1.x, b1.y, b1.z, b1.w};
#pragma unroll
            for (int r = 0; r < 4; r++)
#pragma unroll
                for (int c = 0; c < 8; c++)
                    acc[r][c] += a[r] * bb[c];
        }
        __syncthreads();
    }
    // store to [t, b, h] layout
#pragma unroll
    for (int r = 0; r < 4; r++) {
        int n = n0 + ty * 4 + r;
        int b = n / TT;
        int t = n - b * TT;
        float* dst = OutXW + ((size_t)t * BB + b) * HH + h0 + tx * 8;
        float4 s0 = {acc[r][0], acc[r][1], acc[r][2], acc[r][3]};
        float4 s1 = {acc[r][4], acc[r][5], acc[r][6], acc[r][7]};
        *(float4*)dst = s0;
        *(float4*)(dst + 4) = s1;
    }
}

// ---------------- sequential LIF scan: 1 wave per batch, no barriers ----------------
__global__ __launch_bounds__(64) void scan_lif(const float* __restrict__ tau_syn,
                                               const float* __restrict__ tau_mem,
                                               const float* __restrict__ w_recT,
                                               float* __restrict__ outp) {
    const float DT = 0.001f;
    int b = blockIdx.x;
    int lane = threadIdx.x;
    int off = b * HH + lane;

    float am[4], bs[4];
#pragma unroll
    for (int j = 0; j < 4; j++) {
        am[j] = DT * clip01(tau_mem[lane + 64 * j]);
        bs[j] = DT * clip01(tau_syn[lane + 64 * j]);
    }

    float vv[4] = {0.f, 0.f, 0.f, 0.f};
    float ii[4] = {0.f, 0.f, 0.f, 0.f};
    float racc[4] = {0.f, 0.f, 0.f, 0.f};   // recurrent contribution for the NEXT step
    float zl[4] = {0.f, 0.f, 0.f, 0.f};

    const float* xw = outp;   // xw lives in the out region; overwritten with spikes step by step
    float cur[4][4], nxt[4][4];
#pragma unroll
    for (int u = 0; u < 4; u++)
#pragma unroll
        for (int j = 0; j < 4; j++)
            cur[u][j] = xw[(size_t)u * BH + off + 64 * j];

    for (int t0 = 0; t0 < TT; t0 += 4) {
        // prefetch next chunk of xw (4 steps ahead)
#pragma unroll
        for (int u = 0; u < 4; u++) {
            int tn = t0 + 4 + u;
#pragma unroll
            for (int j = 0; j < 4; j++)
                nxt[u][j] = (tn < TT) ? xw[(size_t)tn * BH + off + 64 * j] : 0.0f;
        }
#pragma unroll
        for (int u = 0; u < 4; u++) {
            int t = t0 + u;
            bool z[4];
#pragma unroll
            for (int j = 0; j < 4; j++) {
                float vd = vv[j] + am[j] * (ii[j] - vv[j]);       // v + DT*tmi*(-v+i)
                float id = ii[j] - bs[j] * ii[j];                 // i - DT*tsi*i
                z[j] = (vd - 1.0f) > 0.0f;
                float zf = z[j] ? 1.0f : 0.0f;
                vv[j] = z[j] ? 0.0f : vd;
                ii[j] = (id + cur[u][j]) + racc[j];               // (i_dec + xw) + rec
                outp[(size_t)t * BH + off + 64 * j] = zf;
                zl[j] = zf;
            }
            // wave-uniform spike masks for this step; build rec term for step t+1
            unsigned long long m0 = __ballot(z[0]);
            unsigned long long m1 = __ballot(z[1]);
            unsigned long long m2 = __ballot(z[2]);
            unsigned long long m3 = __ballot(z[3]);
            racc[0] = racc[1] = racc[2] = racc[3] = 0.0f;
            unsigned long long mm[4] = {m0, m1, m2, m3};
#pragma unroll
            for (int w = 0; w < 4; w++) {
                unsigned long long m = mm[w];
                while (m) {
                    int bit = __builtin_ctzll(m);
                    m &= m - 1;
                    const float* wr = w_recT + (size_t)((w << 6) + bit) * HH + lane;
                    racc[0] += wr[0];
                    racc[1] += wr[64];
                    racc[2] += wr[128];
                    racc[3] += wr[192];
                }
            }
        }
#pragma unroll
        for (int u = 0; u < 4; u++)
#pragma unroll
            for (int j = 0; j < 4; j++)
                cur[u][j] = nxt[u][j];
    }

    // final state: z_f, v_f, i_f
#pragma unroll
    for (int j = 0; j < 4; j++) {
        outp[(size_t)TT * BH + b * HH + lane + 64 * j] = zl[j];
        outp[(size_t)TT * BH + BH + b * HH + lane + 64 * j] = vv[j];
        outp[(size_t)TT * BH + 2 * BH + b * HH + lane + 64 * j] = ii[j];
    }
}

extern "C" void kernel_launch(void* const* d_in, const int* in_sizes, int n_in,
                              void* d_out, int out_size, void* d_ws, size_t ws_size,
                              hipStream_t stream) {
    const float* x       = (const float*)d_in[0];
    const float* w_in    = (const float*)d_in[1];
    const float* w_rec   = (const float*)d_in[2];
    const float* tau_syn = (const float*)d_in[3];
    const float* tau_mem = (const float*)d_in[4];
    float* out = (float*)d_out;

    float* w_inT  = (float*)d_ws;           // 65536 floats
    float* w_recT = w_inT + HH * HH;        // 65536 floats

    transpose2<<<256, 256, 0, stream>>>(w_in, w_rec, w_inT, w_recT);

    dim3 ggrid((BB * TT) / BM, HH / BN);    // (2000, 2)
    gemm_xw<<<ggrid, 256, 0, stream>>>(x, w_inT, out);

    scan_lif<<<BB, 64, 0, stream>>>(tau_syn, tau_mem, w_recT, out);
}

// Round 2
// 577.230 us; speedup vs baseline: 1.3237x; 1.3237x over previous
//
#include <hip/hip_runtime.h>

#define TT 2000
#define BB 64
#define HH 256
#define BH (BB*HH)

__device__ __forceinline__ float clip01(float x) { return fminf(fmaxf(x, 0.0f), 1.0f); }

// ---------------- transpose both weight matrices (256KB each) ----------------
__global__ void transpose2(const float* __restrict__ w_in, const float* __restrict__ w_rec,
                           float* __restrict__ w_inT, float* __restrict__ w_recT) {
    int idx = blockIdx.x * 256 + threadIdx.x;   // 65536 per matrix
    int k = idx >> 8, h = idx & 255;
    w_inT[idx]  = w_in[h * HH + k];             // w_inT[k][h] = w_in[h][k]
    w_recT[idx] = w_rec[h * HH + k];
}

// ---------------- f32 GEMM: xw[n,h] = sum_k X[n,k] * w_inT[k,h] ----------------
// n = b*T + t (input row order). Output written to out region at [t, b, h].
// K-accumulation strictly sequential k=0..255 per output (bitwise-stable).
#define BM 128
#define BN 128
#define BK 32
__global__ __launch_bounds__(256) void gemm_xw(const float* __restrict__ X,
                                               const float* __restrict__ WT,
                                               float* __restrict__ OutXW) {
    __shared__ __align__(16) float XsT[BK][BM + 4];   // transposed: [k][row]
    __shared__ __align__(16) float Ws[BK][BN + 4];    // [k][col]
    int tid = threadIdx.x;
    int n0 = blockIdx.x * BM;
    int h0 = blockIdx.y * BN;
    int ty = tid >> 4, tx = tid & 15;   // thread tile: rows ty*8.., cols tx*8..
    float acc[8][8] = {};

    for (int kc = 0; kc < HH; kc += BK) {
        // load X tile 128x32 (transposed into LDS)
        {
            int r = tid & 127, kseg = (tid >> 7) * 16;
            const float* src = X + (size_t)(n0 + r) * HH + kc + kseg;
#pragma unroll
            for (int q = 0; q < 4; q++) {
                float4 xv = *(const float4*)(src + q * 4);
                XsT[kseg + q * 4 + 0][r] = xv.x;
                XsT[kseg + q * 4 + 1][r] = xv.y;
                XsT[kseg + q * 4 + 2][r] = xv.z;
                XsT[kseg + q * 4 + 3][r] = xv.w;
            }
        }
        // load W tile 32x128 (contiguous from pre-transposed WT)
        {
            int krow = tid >> 3, cs = (tid & 7) * 16;
            const float* src = WT + (size_t)(kc + krow) * HH + h0 + cs;
#pragma unroll
            for (int q = 0; q < 4; q++) {
                float4 wv = *(const float4*)(src + q * 4);
                *(float4*)&Ws[krow][cs + q * 4] = wv;
            }
        }
        __syncthreads();
#pragma unroll 4
        for (int kk = 0; kk < BK; kk++) {
            float4 a0 = *(const float4*)&XsT[kk][ty * 8];
            float4 a1 = *(const float4*)&XsT[kk][ty * 8 + 4];
            float4 b0 = *(const float4*)&Ws[kk][tx * 8];
            float4 b1 = *(const float4*)&Ws[kk][tx * 8 + 4];
            float a[8] = {a0.x, a0.y, a0.z, a0.w, a1.x, a1.y, a1.z, a1.w};
            float bb[8] = {b0.x, b0.y, b0.z, b0.w, b1.x, b1.y, b1.z, b1.w};
#pragma unroll
            for (int r = 0; r < 8; r++)
#pragma unroll
                for (int c = 0; c < 8; c++)
                    acc[r][c] += a[r] * bb[c];
        }
        __syncthreads();
    }
    // store to [t, b, h] layout
#pragma unroll
    for (int r = 0; r < 8; r++) {
        int n = n0 + ty * 8 + r;
        int b = n / TT;
        int t = n - b * TT;
        float* dst = OutXW + ((size_t)t * BB + b) * HH + h0 + tx * 8;
        float4 s0 = {acc[r][0], acc[r][1], acc[r][2], acc[r][3]};
        float4 s1 = {acc[r][4], acc[r][5], acc[r][6], acc[r][7]};
        *(float4*)dst = s0;
        *(float4*)(dst + 4) = s1;
    }
}

// ---------------- sequential LIF scan: 1 wave per batch, no barriers ----------------
// 16-step software pipeline: two 8-step register chunks (static names), reload each
// slot right after consumption (prefetch distance = 16 steps > HBM latency).
// Spike store reuses the same 32-bit element index as the xw load (same address).

// One LIF step. BUF/IDX are the chunk arrays; U is a literal 0..7; PRE: reload?
#define STEP(BUF, IDX, U, PRE)                                                      \
    do {                                                                            \
        bool z[4];                                                                  \
        _Pragma("unroll")                                                           \
        for (int j = 0; j < 4; j++) {                                               \
            float vd = vv[j] + am[j] * (ii[j] - vv[j]);     /* v + DT*tmi*(-v+i) */ \
            float id = ii[j] - bs[j] * ii[j];               /* i - DT*tsi*i    */   \
            z[j] = (vd - 1.0f) > 0.0f;                                              \
            float zf = z[j] ? 1.0f : 0.0f;                                          \
            vv[j] = z[j] ? 0.0f : vd;                                               \
            ii[j] = (id + BUF[U][j]) + racc[j];             /* (i_dec+xw)+rec */    \
            __builtin_nontemporal_store(zf, &outp[IDX[U] + j * 64]);                \
            zl[j] = zf;                                                             \
        }                                                                           \
        if (PRE) {                                                                  \
            IDX[U] += 16 * BH;                                                      \
            _Pragma("unroll")                                                       \
            for (int j = 0; j < 4; j++)                                             \
                BUF[U][j] = outp[IDX[U] + j * 64];                                  \
        }                                                                           \
        unsigned long long m0 = __ballot(z[0]);                                     \
        unsigned long long m1 = __ballot(z[1]);                                     \
        unsigned long long m2 = __ballot(z[2]);                                     \
        unsigned long long m3 = __ballot(z[3]);                                     \
        racc[0] = 0.0f; racc[1] = 0.0f; racc[2] = 0.0f; racc[3] = 0.0f;             \
        if ((m0 | m1 | m2 | m3) != 0ull) {                                          \
            unsigned long long m;                                                   \
            m = m0;                                                                 \
            while (m) { int bit = __builtin_ctzll(m); m &= m - 1;                   \
                const float* wr = w_recT + (size_t)(bit) * HH + lane;               \
                racc[0] += wr[0]; racc[1] += wr[64];                                \
                racc[2] += wr[128]; racc[3] += wr[192]; }                           \
            m = m1;                                                                 \
            while (m) { int bit = __builtin_ctzll(m); m &= m - 1;                   \
                const float* wr = w_recT + (size_t)(64 + bit) * HH + lane;          \
                racc[0] += wr[0]; racc[1] += wr[64];                                \
                racc[2] += wr[128]; racc[3] += wr[192]; }                           \
            m = m2;                                                                 \
            while (m) { int bit = __builtin_ctzll(m); m &= m - 1;                   \
                const float* wr = w_recT + (size_t)(128 + bit) * HH + lane;         \
                racc[0] += wr[0]; racc[1] += wr[64];                                \
                racc[2] += wr[128]; racc[3] += wr[192]; }                           \
            m = m3;                                                                 \
            while (m) { int bit = __builtin_ctzll(m); m &= m - 1;                   \
                const float* wr = w_recT + (size_t)(192 + bit) * HH + lane;         \
                racc[0] += wr[0]; racc[1] += wr[64];                                \
                racc[2] += wr[128]; racc[3] += wr[192]; }                           \
        }                                                                           \
    } while (0)

#define PROC8(BUF, IDX, PRE)                                                        \
    do {                                                                            \
        STEP(BUF, IDX, 0, PRE); STEP(BUF, IDX, 1, PRE);                             \
        STEP(BUF, IDX, 2, PRE); STEP(BUF, IDX, 3, PRE);                             \
        STEP(BUF, IDX, 4, PRE); STEP(BUF, IDX, 5, PRE);                             \
        STEP(BUF, IDX, 6, PRE); STEP(BUF, IDX, 7, PRE);                             \
    } while (0)

__global__ __launch_bounds__(64) void scan_lif(const float* __restrict__ tau_syn,
                                               const float* __restrict__ tau_mem,
                                               const float* __restrict__ w_recT,
                                               float* __restrict__ outp) {
    const float DT = 0.001f;
    int b = blockIdx.x;
    int lane = threadIdx.x;
    int off = b * HH + lane;

    float am[4], bs[4];
#pragma unroll
    for (int j = 0; j < 4; j++) {
        am[j] = DT * clip01(tau_mem[lane + 64 * j]);
        bs[j] = DT * clip01(tau_syn[lane + 64 * j]);
    }

    float vv[4] = {0.f, 0.f, 0.f, 0.f};
    float ii[4] = {0.f, 0.f, 0.f, 0.f};
    float racc[4] = {0.f, 0.f, 0.f, 0.f};   // recurrent contribution for the NEXT step
    float zl[4] = {0.f, 0.f, 0.f, 0.f};

    unsigned idxA[8], idxB[8];
    float bufA[8][4], bufB[8][4];
#pragma unroll
    for (int u = 0; u < 8; u++) {
        idxA[u] = (unsigned)(u * BH + off);
        idxB[u] = (unsigned)((8 + u) * BH + off);
#pragma unroll
        for (int j = 0; j < 4; j++) {
            bufA[u][j] = outp[idxA[u] + j * 64];
            bufB[u][j] = outp[idxB[u] + j * 64];
        }
    }

    for (int it = 0; it < 124; ++it) {
        PROC8(bufA, idxA, 1);
        PROC8(bufB, idxB, 1);
    }
    PROC8(bufA, idxA, 0);   // steps 1984..1991, no prefetch
    PROC8(bufB, idxB, 0);   // steps 1992..1999

    // final state: z_f, v_f, i_f
#pragma unroll
    for (int j = 0; j < 4; j++) {
        outp[(size_t)TT * BH + b * HH + lane + 64 * j] = zl[j];
        outp[(size_t)TT * BH + BH + b * HH + lane + 64 * j] = vv[j];
        outp[(size_t)TT * BH + 2 * BH + b * HH + lane + 64 * j] = ii[j];
    }
}

extern "C" void kernel_launch(void* const* d_in, const int* in_sizes, int n_in,
                              void* d_out, int out_size, void* d_ws, size_t ws_size,
                              hipStream_t stream) {
    const float* x       = (const float*)d_in[0];
    const float* w_in    = (const float*)d_in[1];
    const float* w_rec   = (const float*)d_in[2];
    const float* tau_syn = (const float*)d_in[3];
    const float* tau_mem = (const float*)d_in[4];
    float* out = (float*)d_out;

    float* w_inT  = (float*)d_ws;           // 65536 floats
    float* w_recT = w_inT + HH * HH;        // 65536 floats

    transpose2<<<256, 256, 0, stream>>>(w_in, w_rec, w_inT, w_recT);

    dim3 ggrid((BB * TT) / BM, HH / BN);    // (1000, 2)
    gemm_xw<<<ggrid, 256, 0, stream>>>(x, w_inT, out);

    scan_lif<<<BB, 64, 0, stream>>>(tau_syn, tau_mem, w_recT, out);
}